// Round 6
// baseline (735.034 us; speedup 1.0000x reference)
//
#include <hip/hip_runtime.h>
#include <stdint.h>

// ---------------------------------------------------------------------------
// PSPModule: pool(1,2,3,6) -> conv1x1+BN+lrelu -> bilinear upsample -> concat
//            -> conv3x3 (bf16 MFMA implicit GEMM) -> BN+lrelu
// Round 6: conv3 switched to 32x32x16 MFMA (higher FLOP/cyc, 4 live frags per
// k-step instead of 16 -> compiler can pipeline B loads across taps). pk
// repacked to 32x32 fragment order. conv1x1 rewritten coalesced (lanes over K,
// xs in registers, shuffle reduce, plain stores).
// ---------------------------------------------------------------------------

typedef short short8 __attribute__((ext_vector_type(8)));
typedef float f32x4 __attribute__((ext_vector_type(4)));
typedef float f32x16 __attribute__((ext_vector_type(16)));
typedef unsigned short us4 __attribute__((ext_vector_type(4)));

#define PADW   66
#define PLANE  (PADW*PADW)        // 4356 slots of 64ch
#define PLANE_ELEMS ((size_t)PLANE*64)

// workspace layout (bytes)
#define POOLED_OFF  0u                       // float[2*50*2048]        819200
#define YS_OFF      819200u                  // float[51200]            204800
#define STATS_OFF   1024000u                 // float[1024]             4096
#define CAT_OFF     1048576u                 // bf16[128*4356*64]       71368704
#define CAT_BYTES   71368704u
#define PACKED_OFF  (CAT_OFF + CAT_BYTES)    // bf16[576*4*128*64]      37748736
#define PACKED_BYTES 37748736u
#define CBUF_OFF    (PACKED_OFF + PACKED_BYTES) // float[8192*512]      16777216
#define CBUF_BYTES  16777216u

__device__ __forceinline__ unsigned short f2bf(float x) {
  unsigned int u = __float_as_uint(x);
  unsigned int r = (u + 0x7fffu + ((u >> 16) & 1u)) >> 16;
  return (unsigned short)r;
}

__device__ __forceinline__ void load_lds16(const void* g, uint32_t lds_off) {
  __builtin_amdgcn_global_load_lds(
      (__attribute__((address_space(1))) void*)(uintptr_t)g,
      (__attribute__((address_space(3))) void*)(uintptr_t)lds_off,
      16, 0, 0);
}

// ---------------------------------------------------------------------------
// 1) adaptive avg pool: one block per (n,c) plane; shuffle + row-segment LDS
// ---------------------------------------------------------------------------
__global__ __launch_bounds__(256) void pool_kernel(const float* __restrict__ feats,
                                                   float* __restrict__ pooled) {
  __shared__ float rowtot[64];
  __shared__ float rowseg2[64][2];
  __shared__ float rowseg3[64][3];
  __shared__ float rowseg6[64][6];
  const int t = threadIdx.x;
  const int b = blockIdx.x;                 // n*2048 + c
  const float* plane = feats + (size_t)b * 4096;
  const int h = t >> 2, w0 = (t & 3) << 4;
  const int ws3[3] = {0, 21, 42}, we3[3] = {22, 43, 64};
  const int ws6[6] = {0, 10, 21, 32, 42, 53}, we6[6] = {11, 22, 32, 43, 54, 64};
  float p3[3] = {0.f, 0.f, 0.f};
  float p6[6] = {0.f, 0.f, 0.f, 0.f, 0.f, 0.f};
  float tot = 0.f;
  const float4* row = (const float4*)(plane + h * 64 + w0);
#pragma unroll
  for (int i4 = 0; i4 < 4; ++i4) {
    float4 v = row[i4];
    float vals[4] = {v.x, v.y, v.z, v.w};
#pragma unroll
    for (int j = 0; j < 4; ++j) {
      const int w = w0 + i4 * 4 + j;
      const float x = vals[j];
      tot += x;
#pragma unroll
      for (int q = 0; q < 3; ++q) if (w >= ws3[q] && w < we3[q]) p3[q] += x;
#pragma unroll
      for (int q = 0; q < 6; ++q) if (w >= ws6[q] && w < we6[q]) p6[q] += x;
    }
  }
  float pair = tot + __shfl_down(tot, 1, 4);
  float tot4 = pair + __shfl_down(pair, 2, 4);
#pragma unroll
  for (int q = 0; q < 3; ++q) {
    p3[q] += __shfl_down(p3[q], 1, 4);
    p3[q] += __shfl_down(p3[q], 2, 4);
  }
#pragma unroll
  for (int q = 0; q < 6; ++q) {
    p6[q] += __shfl_down(p6[q], 1, 4);
    p6[q] += __shfl_down(p6[q], 2, 4);
  }
  if ((t & 3) == 0) {
    rowtot[h] = tot4;
    rowseg2[h][0] = pair;
#pragma unroll
    for (int q = 0; q < 3; ++q) rowseg3[h][q] = p3[q];
#pragma unroll
    for (int q = 0; q < 6; ++q) rowseg6[h][q] = p6[q];
  }
  if ((t & 3) == 2) rowseg2[h][1] = pair;
  __syncthreads();
  if (t < 50) {
    float s = 0.f;
    float inv;
    if (t == 0) {
      for (int r = 0; r < 64; ++r) s += rowtot[r];
      inv = 1.0f / 4096.0f;
    } else if (t < 5) {
      const int qh = (t - 1) >> 1, qw = (t - 1) & 1;
      for (int r = qh * 32; r < qh * 32 + 32; ++r) s += rowseg2[r][qw];
      inv = 1.0f / 1024.0f;
    } else if (t < 14) {
      const int p = t - 5, qh = p / 3, qw = p % 3;
      for (int r = ws3[qh]; r < we3[qh]; ++r) s += rowseg3[r][qw];
      inv = 1.0f / ((float)(we3[qh] - ws3[qh]) * (float)(we3[qw] - ws3[qw]));
    } else {
      const int p = t - 14, qh = p / 6, qw = p % 6;
      for (int r = ws6[qh]; r < we6[qh]; ++r) s += rowseg6[r][qw];
      inv = 1.0f / ((float)(we6[qh] - ws6[qh]) * (float)(we6[qw] - ws6[qw]));
    }
    const int n = b >> 11, c = b & 2047;
    pooled[((size_t)(n * 50 + t)) * 2048 + c] = s * inv;
  }
}

// ---------------------------------------------------------------------------
// 2) conv1x1: grid (col 100) x (og 4). Lanes span K (coalesced W float4),
//    xs held in 32 regs/lane, 64-lane shuffle reduce, plain stores.
// ---------------------------------------------------------------------------
__global__ __launch_bounds__(256) void conv1x1_kernel(
    const float* __restrict__ pooled, const float* __restrict__ w0,
    const float* __restrict__ w1, const float* __restrict__ w2,
    const float* __restrict__ w3, float* __restrict__ ys) {
  const int t = threadIdx.x;
  const int lane = t & 63;
  const int w = t >> 6;
  const int col = blockIdx.x >> 2;         // n*50 + spos
  const int og = blockIdx.x & 3;
  const int n = col / 50, spos = col % 50;
  float4 xv[8];
  const float4* xp = (const float4*)(pooled + (size_t)col * 2048);
#pragma unroll
  for (int i = 0; i < 8; ++i) xv[i] = xp[i * 64 + lane];
  int si, pos;
  if (spos < 1)       { si = 0; pos = spos; }
  else if (spos < 5)  { si = 1; pos = spos - 1; }
  else if (spos < 14) { si = 2; pos = spos - 5; }
  else                { si = 3; pos = spos - 14; }
  const float* Wt = (si == 0) ? w0 : (si == 1) ? w1 : (si == 2) ? w2 : w3;
  const int ssarr[4] = {1, 4, 9, 36};
  const int ybase[4] = {0, 1024, 5120, 14336};
  const int ss = ssarr[si];
  for (int oi = 0; oi < 32; ++oi) {
    const int o = og * 128 + w * 32 + oi;
    const float4* wr = (const float4*)(Wt + (size_t)o * 2048);
    float a = 0.f;
#pragma unroll
    for (int i = 0; i < 8; ++i) {
      float4 wv = wr[i * 64 + lane];
      a += wv.x * xv[i].x + wv.y * xv[i].y + wv.z * xv[i].z + wv.w * xv[i].w;
    }
#pragma unroll
    for (int d = 1; d < 64; d <<= 1) a += __shfl_xor(a, d);
    if (lane == 0)
      ys[ybase[si] + (size_t)(n * 512 + o) * ss + pos] = a;
  }
}

// ---------------------------------------------------------------------------
// 3) BN (batch stats) + leaky_relu on tiny pooled maps, in place
// ---------------------------------------------------------------------------
__global__ __launch_bounds__(512) void bn_small_kernel(
    float* __restrict__ ys, const float* __restrict__ g0, const float* __restrict__ b0,
    const float* __restrict__ g1, const float* __restrict__ b1,
    const float* __restrict__ g2, const float* __restrict__ b2,
    const float* __restrict__ g3, const float* __restrict__ b3) {
  const int si = blockIdx.x;
  const int o = threadIdx.x;               // 0..511
  const int ssarr[4] = {1, 4, 9, 36};
  const int ybase[4] = {0, 1024, 5120, 14336};
  const int ss = ssarr[si];
  const int M = 2 * ss;
  float* base0 = ys + ybase[si] + (size_t)o * ss;
  float* base1 = ys + ybase[si] + (size_t)(512 + o) * ss;
  float sum = 0.f, sq = 0.f;
  for (int p = 0; p < ss; ++p) { float v = base0[p]; sum += v; sq += v * v; }
  for (int p = 0; p < ss; ++p) { float v = base1[p]; sum += v; sq += v * v; }
  const float mean = sum / (float)M;
  float var = sq / (float)M - mean * mean;
  var = fmaxf(var, 0.0f);
  const float rstd = rsqrtf(var + 1e-5f);
  const float* gp = (si == 0) ? g0 : (si == 1) ? g1 : (si == 2) ? g2 : g3;
  const float* bp = (si == 0) ? b0 : (si == 1) ? b1 : (si == 2) ? b2 : b3;
  const float sc = rstd * gp[o];
  const float sh = bp[o] - mean * sc;
  for (int p = 0; p < ss; ++p) {
    float y = base0[p] * sc + sh; base0[p] = (y >= 0.f) ? y : 0.01f * y;
  }
  for (int p = 0; p < ss; ++p) {
    float y = base1[p] * sc + sh; base1[p] = (y >= 0.f) ? y : 0.01f * y;
  }
}

// ---------------------------------------------------------------------------
// 3.5) zero the 1-pixel borders of all 128 cat planes (swizzle-invariant)
// ---------------------------------------------------------------------------
__global__ __launch_bounds__(256) void zero_borders(unsigned short* __restrict__ cat) {
  const int t = threadIdx.x;
  unsigned short* base = cat + (size_t)blockIdx.x * PLANE_ELEMS;
  for (int idx = t; idx < 4160; idx += 256) {   // 260 border slots x 16 us4
    const int slot = idx >> 4, c4 = idx & 15;
    int q;
    if (slot < 66) q = slot;
    else if (slot < 132) q = 65 * 66 + (slot - 66);
    else { const int k = slot - 132; q = (1 + (k >> 1)) * 66 + (k & 1) * 65; }
    us4 z = {0, 0, 0, 0};
    *(us4*)(base + (size_t)q * 64 + c4 * 4) = z;
  }
}

// ---------------------------------------------------------------------------
// 4) bilinear (align_corners) upsample of priors into swizzled bf16 cat
// ---------------------------------------------------------------------------
__global__ __launch_bounds__(256) void fill_priors(const float* __restrict__ ys,
                                                   unsigned short* __restrict__ cat) {
  __shared__ float s0[3072], s1[3072];
  const int t = threadIdx.x;
  const int bx = blockIdx.x;               // n*64 + h
  const int si = blockIdx.y;               // 0..3
  const int n = bx >> 6, h = bx & 63;
  const int sarr[4] = {1, 2, 3, 6};
  const int ssarr[4] = {1, 4, 9, 36};
  const int ybase[4] = {0, 1024, 5120, 14336};
  const int s = sarr[si], ss = ssarr[si];
  const float yc = (float)(h * (s - 1)) / 63.0f;
  int y0 = (int)yc;
  int y1 = (y0 + 1 < s - 1) ? y0 + 1 : s - 1;
  const float wy = yc - (float)y0;
  const float* base = ys + ybase[si] + (size_t)n * 512 * ss;
  for (int idx = t; idx < 512 * s; idx += 256) {
    int o = idx / s, j = idx - o * s;
    s0[idx] = base[(size_t)o * ss + y0 * s + j];
    s1[idx] = base[(size_t)o * ss + y1 * s + j];
  }
  __syncthreads();
  unsigned short* dstbase = cat + (size_t)(n * 64 + si * 8) * PLANE_ELEMS;
  for (int k = 0; k < 32; ++k) {
    const int g = t + k * 256;             // 0..8191
    const int cbp = g >> 10, rem = g & 1023;
    const int w = rem >> 4, c4 = rem & 15;
    const float xc = (float)(w * (s - 1)) / 63.0f;
    int x0 = (int)xc;
    int x1 = (x0 + 1 < s - 1) ? x0 + 1 : s - 1;
    const float wx = xc - (float)x0;
    unsigned short vv[4];
#pragma unroll
    for (int j = 0; j < 4; ++j) {
      const int o = cbp * 64 + c4 * 4 + j;
      const float a = s0[o * s + x0], b2 = s0[o * s + x1];
      const float c = s1[o * s + x0], d = s1[o * s + x1];
      const float top = a + (b2 - a) * wx;
      const float bot = c + (d - c) * wx;
      vv[j] = f2bf(top + (bot - top) * wy);
    }
    us4 ov; ov.x = vv[0]; ov.y = vv[1]; ov.z = vv[2]; ov.w = vv[3];
    const int q = (h + 1) * PADW + (w + 1);
    const int phys = (((c4 >> 1) ^ (q & 7)) << 3) + ((c4 & 1) << 2);
    *(us4*)(dstbase + (size_t)cbp * PLANE_ELEMS + (size_t)q * 64 + phys) = ov;
  }
}

// ---------------------------------------------------------------------------
// 5) feats -> swizzled bf16 cat (NCHW -> blocked, LDS transpose)
// ---------------------------------------------------------------------------
__global__ __launch_bounds__(256) void fill_feats(const float* __restrict__ feats,
                                                  unsigned short* __restrict__ cat) {
  __shared__ float lds[64][65];
  const int t = threadIdx.x;
  const int b = blockIdx.x;                // n*32 + fb
  const int n = b >> 5, fb = b & 31;
  const int h0 = blockIdx.y * 16;
  const float* src = feats + (size_t)(n * 2048 + fb * 64) * 4096;
  unsigned short* dst = cat + (size_t)(n * 64 + 32 + fb) * PLANE_ELEMS;
  for (int h = h0; h < h0 + 16; ++h) {
#pragma unroll
    for (int k = 0; k < 4; ++k) {
      const int idx4 = t + k * 256;        // 0..1023
      const int c = idx4 >> 4, w4 = idx4 & 15;
      float4 v = ((const float4*)(src + (size_t)c * 4096 + h * 64))[w4];
      lds[c][w4 * 4 + 0] = v.x; lds[c][w4 * 4 + 1] = v.y;
      lds[c][w4 * 4 + 2] = v.z; lds[c][w4 * 4 + 3] = v.w;
    }
    __syncthreads();
#pragma unroll
    for (int k = 0; k < 4; ++k) {
      const int idx4 = t + k * 256;
      const int w = idx4 >> 4, c4 = idx4 & 15;
      unsigned short vv[4];
#pragma unroll
      for (int j = 0; j < 4; ++j) vv[j] = f2bf(lds[c4 * 4 + j][w]);
      us4 ov; ov.x = vv[0]; ov.y = vv[1]; ov.z = vv[2]; ov.w = vv[3];
      const int q = (h + 1) * PADW + (w + 1);
      const int phys = (((c4 >> 1) ^ (q & 7)) << 3) + ((c4 & 1) << 2);
      *(us4*)(dst + (size_t)q * 64 + phys) = ov;
    }
    __syncthreads();
  }
}

// ---------------------------------------------------------------------------
// 6) pack wb fp32 [o][c][3][3] -> bf16 32x32-fragment-ordered pk:
//    frag f = wn*8 + jb*4 + ks  (o = ot*128+wn*64+jb*32+(l&31),
//    k = ks*16 + (l>>5)*8 + e); record = f*512 + l*8 + e
// ---------------------------------------------------------------------------
__global__ __launch_bounds__(256) void pack_w(const float* __restrict__ wb,
                                              unsigned short* __restrict__ pk) {
  __shared__ float lds[16][577];
  const int t = threadIdx.x;
  const int cb = blockIdx.x;               // 0..63
  const int ot = blockIdx.y;               // 0..3
  for (int ch8 = 0; ch8 < 8; ++ch8) {
    const int o0 = ot * 128 + ch8 * 16;
    __syncthreads();
#pragma unroll
    for (int k = 0; k < 9; ++k) {
      const int idx4 = t + k * 256;        // 0..2303
      const int os = idx4 / 144, c4 = idx4 - os * 144;
      float4 v = ((const float4*)(wb + (size_t)(o0 + os) * 36864 + cb * 576))[c4];
      lds[os][c4 * 4 + 0] = v.x; lds[os][c4 * 4 + 1] = v.y;
      lds[os][c4 * 4 + 2] = v.z; lds[os][c4 * 4 + 3] = v.w;
    }
    __syncthreads();
#pragma unroll
    for (int k = 0; k < 9; ++k) {
      const int g = t + k * 256;           // 0..2303 = tap(9) x os(16) x c4(16)
      const int c4 = g & 15;               // k_local = c4*4 + j
      const int os = (g >> 4) & 15;        // o_local = ch8*16 + os
      const int tap = g >> 8;
      unsigned short vv[4];
#pragma unroll
      for (int j = 0; j < 4; ++j) vv[j] = f2bf(lds[os][(c4 * 4 + j) * 9 + tap]);
      us4 ov; ov.x = vv[0]; ov.y = vv[1]; ov.z = vv[2]; ov.w = vv[3];
      const int o_local = ch8 * 16 + os;
      const int wn = o_local >> 6, jb = (o_local >> 5) & 1, l5 = o_local & 31;
      const int ks = c4 >> 2, lhi = (c4 >> 1) & 1, e0 = (c4 & 1) * 4;
      const int f = wn * 8 + jb * 4 + ks;
      const size_t dst = ((size_t)(cb * 9 + tap) * 4 + ot) * 8192 +
                         (size_t)f * 512 + (size_t)(lhi * 32 + l5) * 8 + e0;
      *(us4*)(pk + dst) = ov;
    }
  }
}

// ---------------------------------------------------------------------------
// 7) conv3x3 implicit GEMM: 32x32x16 bf16 MFMA, A staged once per cb (4 padded
//    rows cover all 9 taps), B register-direct from fragment-ordered pk.
//    128x128 tile, split-K=4, atomicAdd epilogue.
// ---------------------------------------------------------------------------
__global__ __launch_bounds__(256, 3) void conv3_kernel(
    const unsigned short* __restrict__ cat, const unsigned short* __restrict__ pk,
    float* __restrict__ C) {
  __shared__ unsigned short As[264 * 64];  // 4 rows x 66 slots x 64ch = 33792 B
  const int t = threadIdx.x;
  const int lane = t & 63;
  const int wave = t >> 6;
  const int l5 = lane & 31;
  const int lhi = lane >> 5;
  const int bx = blockIdx.x;               // 0..63  M tile (128 pixels = 2 rows)
  const int by = blockIdx.y;               // 0..3   N tile (128 out ch)
  const int bz = blockIdx.z;               // 0..3   split-K (16 cblk each)
  const int n = bx >> 5;
  const int h0 = (bx & 31) << 1;
  const int wm = wave >> 1, wn = wave & 1;

  f32x16 acc[2][2];
#pragma unroll
  for (int i = 0; i < 2; ++i)
#pragma unroll
    for (int j = 0; j < 2; ++j) acc[i][j] = (f32x16)0.0f;

  const uint32_t as_base = (uint32_t)(uintptr_t)(&As[0]);
  const uint8_t* catb = (const uint8_t*)cat;
  const unsigned short* pkw = pk + (size_t)by * 8192 + (size_t)wn * 4096 +
                              (size_t)lane * 8;

  for (int cb2 = 0; cb2 < 16; ++cb2) {
    const int cb = bz * 16 + cb2;
    const uint8_t* srcA = catb +
        ((size_t)(n * 64 + cb) * PLANE_ELEMS + (size_t)(h0 * PADW) * 64) * 2;
    __syncthreads();                       // protect As reuse
    for (int idx = wave; idx < 33; idx += 4)
      load_lds16(srcA + (size_t)idx * 1024 + lane * 16,
                 as_base + (uint32_t)idx * 1024 + lane * 16);
    __syncthreads();
#pragma unroll
    for (int tap = 0; tap < 9; ++tap) {
      const int dh = tap / 3 - 1, dw = tap % 3 - 1;
      const int r = wm + 1 + dh;           // As row 0..3
      const unsigned short* pkt = pkw + (size_t)(cb * 9 + tap) * 32768;
      short8 bf[2][4];
#pragma unroll
      for (int jb = 0; jb < 2; ++jb)
#pragma unroll
        for (int ks = 0; ks < 4; ++ks)
          bf[jb][ks] = *(const short8*)(pkt + (jb * 4 + ks) * 512);
      short8 af[2][4];
#pragma unroll
      for (int im = 0; im < 2; ++im) {
        const int s = im * 32 + l5 + 1 + dw;
        const int q = (h0 + r) * PADW + s; // slot idx -> swizzle key
        const int key = q & 7;
        const unsigned short* rowp = As + ((r * 66 + s) << 6);
#pragma unroll
        for (int ks = 0; ks < 4; ++ks)
          af[im][ks] = *(const short8*)(rowp + (((ks * 2 + lhi) ^ key) << 3));
      }
#pragma unroll
      for (int ks = 0; ks < 4; ++ks)
#pragma unroll
        for (int im = 0; im < 2; ++im)
#pragma unroll
          for (int jb = 0; jb < 2; ++jb)
            acc[im][jb] = __builtin_amdgcn_mfma_f32_32x32x16_bf16(
                af[im][ks], bf[jb][ks], acc[im][jb], 0, 0, 0);
    }
  }
  // epilogue: 32x32 C/D layout col = lane&31, row = (r&3) + 8*(r>>2) + 4*lhi
#pragma unroll
  for (int im = 0; im < 2; ++im) {
#pragma unroll
    for (int jb = 0; jb < 2; ++jb) {
      const int o = by * 128 + wn * 64 + jb * 32 + l5;
#pragma unroll
      for (int r = 0; r < 16; ++r) {
        const int row = (r & 3) + 8 * (r >> 2) + 4 * lhi;
        const size_t p = (size_t)bx * 128 + wm * 64 + im * 32 + row;
        atomicAdd(&C[p * 512 + o], acc[im][jb][r]);
      }
    }
  }
}

// ---------------------------------------------------------------------------
// 8) batch-norm stats over pixels for each of 512 channels
// ---------------------------------------------------------------------------
__global__ __launch_bounds__(256) void bn_stats_kernel(const float* __restrict__ C,
                                                       float* __restrict__ stats) {
  const int t = threadIdx.x;
  const int p0 = blockIdx.x * 32;
  float s0 = 0.f, q0 = 0.f, s1 = 0.f, q1 = 0.f;
  for (int p = p0; p < p0 + 32; ++p) {
    const float a = C[(size_t)p * 512 + t];
    const float b = C[(size_t)p * 512 + t + 256];
    s0 += a; q0 += a * a; s1 += b; q1 += b * b;
  }
  atomicAdd(&stats[t], s0);
  atomicAdd(&stats[t + 256], s1);
  atomicAdd(&stats[512 + t], q0);
  atomicAdd(&stats[512 + t + 256], q1);
}

// ---------------------------------------------------------------------------
// 9) BN apply + leaky_relu + NHWC -> NCHW transpose into d_out
// ---------------------------------------------------------------------------
__global__ __launch_bounds__(256) void bn_apply_kernel(
    const float* __restrict__ C, const float* __restrict__ stats,
    const float* __restrict__ gb, const float* __restrict__ bb,
    float* __restrict__ out) {
  __shared__ float lds[64][65];
  __shared__ float sc_s[64], sh_s[64];
  const int t = threadIdx.x;
  const int p0 = blockIdx.x * 64;          // 64 pixels = one (n,h) row
  const int o0 = blockIdx.y * 64;
  if (t < 64) {
    const int o = o0 + t;
    const float mean = stats[o] * (1.0f / 8192.0f);
    float var = stats[512 + o] * (1.0f / 8192.0f) - mean * mean;
    var = fmaxf(var, 0.0f);
    const float rstd = rsqrtf(var + 1e-5f);
    const float sc = rstd * gb[o];
    sc_s[t] = sc;
    sh_s[t] = bb[o] - mean * sc;
  }
#pragma unroll
  for (int k = 0; k < 4; ++k) {
    const int idx4 = t + k * 256;
    const int ps = idx4 >> 4, o4 = idx4 & 15;
    float4 v = ((const float4*)(C + (size_t)(p0 + ps) * 512 + o0))[o4];
    lds[ps][o4 * 4 + 0] = v.x; lds[ps][o4 * 4 + 1] = v.y;
    lds[ps][o4 * 4 + 2] = v.z; lds[ps][o4 * 4 + 3] = v.w;
  }
  __syncthreads();
  const int n = p0 >> 12, h = (p0 >> 6) & 63;
#pragma unroll
  for (int k = 0; k < 4; ++k) {
    const int idx4 = t + k * 256;
    const int os = idx4 >> 4, w4 = idx4 & 15;
    const float sc = sc_s[os], sh = sh_s[os];
    float vv[4];
#pragma unroll
    for (int j = 0; j < 4; ++j) {
      float v = lds[w4 * 4 + j][os] * sc + sh;
      vv[j] = (v >= 0.f) ? v : 0.01f * v;
    }
    float4 r; r.x = vv[0]; r.y = vv[1]; r.z = vv[2]; r.w = vv[3];
    *(float4*)(out + ((size_t)(n * 512 + o0 + os)) * 4096 + h * 64 + w4 * 4) = r;
  }
}

// ---------------------------------------------------------------------------
extern "C" void kernel_launch(void* const* d_in, const int* in_sizes, int n_in,
                              void* d_out, int out_size, void* d_ws, size_t ws_size,
                              hipStream_t stream) {
  (void)in_sizes; (void)n_in; (void)out_size; (void)ws_size;
  const float* feats = (const float*)d_in[0];
  const float* w0 = (const float*)d_in[1];
  const float* g0 = (const float*)d_in[2];
  const float* b0 = (const float*)d_in[3];
  const float* w1 = (const float*)d_in[4];
  const float* g1 = (const float*)d_in[5];
  const float* b1 = (const float*)d_in[6];
  const float* w2 = (const float*)d_in[7];
  const float* g2 = (const float*)d_in[8];
  const float* b2 = (const float*)d_in[9];
  const float* w3 = (const float*)d_in[10];
  const float* g3 = (const float*)d_in[11];
  const float* b3 = (const float*)d_in[12];
  const float* wb = (const float*)d_in[13];
  const float* gb = (const float*)d_in[14];
  const float* bb = (const float*)d_in[15];

  uint8_t* ws = (uint8_t*)d_ws;
  float* pooled = (float*)(ws + POOLED_OFF);
  float* ys = (float*)(ws + YS_OFF);
  float* stats = (float*)(ws + STATS_OFF);
  unsigned short* cat = (unsigned short*)(ws + CAT_OFF);
  unsigned short* pk = (unsigned short*)(ws + PACKED_OFF);
  float* C = (float*)(ws + CBUF_OFF);
  float* outp = (float*)d_out;

  hipMemsetAsync(stats, 0, 4096, stream);
  hipMemsetAsync(C, 0, CBUF_BYTES, stream);

  pool_kernel<<<4096, 256, 0, stream>>>(feats, pooled);
  conv1x1_kernel<<<400, 256, 0, stream>>>(pooled, w0, w1, w2, w3, ys);
  bn_small_kernel<<<4, 512, 0, stream>>>(ys, g0, b0, g1, b1, g2, b2, g3, b3);
  zero_borders<<<128, 256, 0, stream>>>(cat);
  fill_priors<<<dim3(128, 4), 256, 0, stream>>>(ys, cat);
  fill_feats<<<dim3(64, 4), 256, 0, stream>>>(feats, cat);
  pack_w<<<dim3(64, 4), 256, 0, stream>>>(wb, pk);
  conv3_kernel<<<dim3(64, 4, 4), 256, 0, stream>>>(cat, pk, C);
  bn_stats_kernel<<<256, 256, 0, stream>>>(C, stats);
  bn_apply_kernel<<<dim3(128, 8), 256, 0, stream>>>(C, stats, gb, bb, outp);
}

// Round 7
// 665.910 us; speedup vs baseline: 1.1038x; 1.1038x over previous
//
#include <hip/hip_runtime.h>
#include <stdint.h>

// ---------------------------------------------------------------------------
// PSPModule: pool(1,2,3,6) -> conv1x1+BN+lrelu -> bilinear upsample -> concat
//            -> conv3x3 (bf16 MFMA implicit GEMM) -> BN+lrelu
// Round 7: r5 conv3 structure (A staged once/cb, B register-direct, 16x16x32)
// + explicit B double-buffer across taps (prefetch tap+1's 8 fragments while
// tap's 32 MFMAs run) + launch_bounds(256,2) so the compiler has registers to
// keep both fragment sets live. 32x32 experiment (r6) reverted.
// ---------------------------------------------------------------------------

typedef short short8 __attribute__((ext_vector_type(8)));
typedef float f32x4 __attribute__((ext_vector_type(4)));
typedef unsigned short us4 __attribute__((ext_vector_type(4)));

#define PADW   66
#define PLANE  (PADW*PADW)        // 4356 slots of 64ch
#define PLANE_ELEMS ((size_t)PLANE*64)

// workspace layout (bytes)
#define POOLED_OFF  0u                       // float[2*50*2048]        819200
#define YS_OFF      819200u                  // float[51200]            204800
#define STATS_OFF   1024000u                 // float[1024]             4096
#define CAT_OFF     1048576u                 // bf16[128*4356*64]       71368704
#define CAT_BYTES   71368704u
#define PACKED_OFF  (CAT_OFF + CAT_BYTES)    // bf16[576*4*128*64]      37748736
#define PACKED_BYTES 37748736u
#define CBUF_OFF    (PACKED_OFF + PACKED_BYTES) // float[8192*512]      16777216
#define CBUF_BYTES  16777216u

__device__ __forceinline__ unsigned short f2bf(float x) {
  unsigned int u = __float_as_uint(x);
  unsigned int r = (u + 0x7fffu + ((u >> 16) & 1u)) >> 16;
  return (unsigned short)r;
}

__device__ __forceinline__ void load_lds16(const void* g, uint32_t lds_off) {
  __builtin_amdgcn_global_load_lds(
      (__attribute__((address_space(1))) void*)(uintptr_t)g,
      (__attribute__((address_space(3))) void*)(uintptr_t)lds_off,
      16, 0, 0);
}

// ---------------------------------------------------------------------------
// 1) adaptive avg pool: one block per (n,c) plane; shuffle + row-segment LDS
// ---------------------------------------------------------------------------
__global__ __launch_bounds__(256) void pool_kernel(const float* __restrict__ feats,
                                                   float* __restrict__ pooled) {
  __shared__ float rowtot[64];
  __shared__ float rowseg2[64][2];
  __shared__ float rowseg3[64][3];
  __shared__ float rowseg6[64][6];
  const int t = threadIdx.x;
  const int b = blockIdx.x;                 // n*2048 + c
  const float* plane = feats + (size_t)b * 4096;
  const int h = t >> 2, w0 = (t & 3) << 4;
  const int ws3[3] = {0, 21, 42}, we3[3] = {22, 43, 64};
  const int ws6[6] = {0, 10, 21, 32, 42, 53}, we6[6] = {11, 22, 32, 43, 54, 64};
  float p3[3] = {0.f, 0.f, 0.f};
  float p6[6] = {0.f, 0.f, 0.f, 0.f, 0.f, 0.f};
  float tot = 0.f;
  const float4* row = (const float4*)(plane + h * 64 + w0);
#pragma unroll
  for (int i4 = 0; i4 < 4; ++i4) {
    float4 v = row[i4];
    float vals[4] = {v.x, v.y, v.z, v.w};
#pragma unroll
    for (int j = 0; j < 4; ++j) {
      const int w = w0 + i4 * 4 + j;
      const float x = vals[j];
      tot += x;
#pragma unroll
      for (int q = 0; q < 3; ++q) if (w >= ws3[q] && w < we3[q]) p3[q] += x;
#pragma unroll
      for (int q = 0; q < 6; ++q) if (w >= ws6[q] && w < we6[q]) p6[q] += x;
    }
  }
  float pair = tot + __shfl_down(tot, 1, 4);
  float tot4 = pair + __shfl_down(pair, 2, 4);
#pragma unroll
  for (int q = 0; q < 3; ++q) {
    p3[q] += __shfl_down(p3[q], 1, 4);
    p3[q] += __shfl_down(p3[q], 2, 4);
  }
#pragma unroll
  for (int q = 0; q < 6; ++q) {
    p6[q] += __shfl_down(p6[q], 1, 4);
    p6[q] += __shfl_down(p6[q], 2, 4);
  }
  if ((t & 3) == 0) {
    rowtot[h] = tot4;
    rowseg2[h][0] = pair;
#pragma unroll
    for (int q = 0; q < 3; ++q) rowseg3[h][q] = p3[q];
#pragma unroll
    for (int q = 0; q < 6; ++q) rowseg6[h][q] = p6[q];
  }
  if ((t & 3) == 2) rowseg2[h][1] = pair;
  __syncthreads();
  if (t < 50) {
    float s = 0.f;
    float inv;
    if (t == 0) {
      for (int r = 0; r < 64; ++r) s += rowtot[r];
      inv = 1.0f / 4096.0f;
    } else if (t < 5) {
      const int qh = (t - 1) >> 1, qw = (t - 1) & 1;
      for (int r = qh * 32; r < qh * 32 + 32; ++r) s += rowseg2[r][qw];
      inv = 1.0f / 1024.0f;
    } else if (t < 14) {
      const int p = t - 5, qh = p / 3, qw = p % 3;
      for (int r = ws3[qh]; r < we3[qh]; ++r) s += rowseg3[r][qw];
      inv = 1.0f / ((float)(we3[qh] - ws3[qh]) * (float)(we3[qw] - ws3[qw]));
    } else {
      const int p = t - 14, qh = p / 6, qw = p % 6;
      for (int r = ws6[qh]; r < we6[qh]; ++r) s += rowseg6[r][qw];
      inv = 1.0f / ((float)(we6[qh] - ws6[qh]) * (float)(we6[qw] - ws6[qw]));
    }
    const int n = b >> 11, c = b & 2047;
    pooled[((size_t)(n * 50 + t)) * 2048 + c] = s * inv;
  }
}

// ---------------------------------------------------------------------------
// 2) conv1x1: grid (col 100) x (og 4). Lanes span K (coalesced W float4),
//    xs held in 32 regs/lane, 64-lane shuffle reduce, plain stores.
// ---------------------------------------------------------------------------
__global__ __launch_bounds__(256) void conv1x1_kernel(
    const float* __restrict__ pooled, const float* __restrict__ w0,
    const float* __restrict__ w1, const float* __restrict__ w2,
    const float* __restrict__ w3, float* __restrict__ ys) {
  const int t = threadIdx.x;
  const int lane = t & 63;
  const int w = t >> 6;
  const int col = blockIdx.x >> 2;         // n*50 + spos
  const int og = blockIdx.x & 3;
  const int n = col / 50, spos = col % 50;
  float4 xv[8];
  const float4* xp = (const float4*)(pooled + (size_t)col * 2048);
#pragma unroll
  for (int i = 0; i < 8; ++i) xv[i] = xp[i * 64 + lane];
  int si, pos;
  if (spos < 1)       { si = 0; pos = spos; }
  else if (spos < 5)  { si = 1; pos = spos - 1; }
  else if (spos < 14) { si = 2; pos = spos - 5; }
  else                { si = 3; pos = spos - 14; }
  const float* Wt = (si == 0) ? w0 : (si == 1) ? w1 : (si == 2) ? w2 : w3;
  const int ssarr[4] = {1, 4, 9, 36};
  const int ybase[4] = {0, 1024, 5120, 14336};
  const int ss = ssarr[si];
  for (int oi = 0; oi < 32; ++oi) {
    const int o = og * 128 + w * 32 + oi;
    const float4* wr = (const float4*)(Wt + (size_t)o * 2048);
    float a = 0.f;
#pragma unroll
    for (int i = 0; i < 8; ++i) {
      float4 wv = wr[i * 64 + lane];
      a += wv.x * xv[i].x + wv.y * xv[i].y + wv.z * xv[i].z + wv.w * xv[i].w;
    }
#pragma unroll
    for (int d = 1; d < 64; d <<= 1) a += __shfl_xor(a, d);
    if (lane == 0)
      ys[ybase[si] + (size_t)(n * 512 + o) * ss + pos] = a;
  }
}

// ---------------------------------------------------------------------------
// 3) BN (batch stats) + leaky_relu on tiny pooled maps, in place
// ---------------------------------------------------------------------------
__global__ __launch_bounds__(512) void bn_small_kernel(
    float* __restrict__ ys, const float* __restrict__ g0, const float* __restrict__ b0,
    const float* __restrict__ g1, const float* __restrict__ b1,
    const float* __restrict__ g2, const float* __restrict__ b2,
    const float* __restrict__ g3, const float* __restrict__ b3) {
  const int si = blockIdx.x;
  const int o = threadIdx.x;               // 0..511
  const int ssarr[4] = {1, 4, 9, 36};
  const int ybase[4] = {0, 1024, 5120, 14336};
  const int ss = ssarr[si];
  const int M = 2 * ss;
  float* base0 = ys + ybase[si] + (size_t)o * ss;
  float* base1 = ys + ybase[si] + (size_t)(512 + o) * ss;
  float sum = 0.f, sq = 0.f;
  for (int p = 0; p < ss; ++p) { float v = base0[p]; sum += v; sq += v * v; }
  for (int p = 0; p < ss; ++p) { float v = base1[p]; sum += v; sq += v * v; }
  const float mean = sum / (float)M;
  float var = sq / (float)M - mean * mean;
  var = fmaxf(var, 0.0f);
  const float rstd = rsqrtf(var + 1e-5f);
  const float* gp = (si == 0) ? g0 : (si == 1) ? g1 : (si == 2) ? g2 : g3;
  const float* bp = (si == 0) ? b0 : (si == 1) ? b1 : (si == 2) ? b2 : b3;
  const float sc = rstd * gp[o];
  const float sh = bp[o] - mean * sc;
  for (int p = 0; p < ss; ++p) {
    float y = base0[p] * sc + sh; base0[p] = (y >= 0.f) ? y : 0.01f * y;
  }
  for (int p = 0; p < ss; ++p) {
    float y = base1[p] * sc + sh; base1[p] = (y >= 0.f) ? y : 0.01f * y;
  }
}

// ---------------------------------------------------------------------------
// 3.5) zero the 1-pixel borders of all 128 cat planes (swizzle-invariant)
// ---------------------------------------------------------------------------
__global__ __launch_bounds__(256) void zero_borders(unsigned short* __restrict__ cat) {
  const int t = threadIdx.x;
  unsigned short* base = cat + (size_t)blockIdx.x * PLANE_ELEMS;
  for (int idx = t; idx < 4160; idx += 256) {   // 260 border slots x 16 us4
    const int slot = idx >> 4, c4 = idx & 15;
    int q;
    if (slot < 66) q = slot;
    else if (slot < 132) q = 65 * 66 + (slot - 66);
    else { const int k = slot - 132; q = (1 + (k >> 1)) * 66 + (k & 1) * 65; }
    us4 z = {0, 0, 0, 0};
    *(us4*)(base + (size_t)q * 64 + c4 * 4) = z;
  }
}

// ---------------------------------------------------------------------------
// 4) bilinear (align_corners) upsample of priors into swizzled bf16 cat
// ---------------------------------------------------------------------------
__global__ __launch_bounds__(256) void fill_priors(const float* __restrict__ ys,
                                                   unsigned short* __restrict__ cat) {
  __shared__ float s0[3072], s1[3072];
  const int t = threadIdx.x;
  const int bx = blockIdx.x;               // n*64 + h
  const int si = blockIdx.y;               // 0..3
  const int n = bx >> 6, h = bx & 63;
  const int sarr[4] = {1, 2, 3, 6};
  const int ssarr[4] = {1, 4, 9, 36};
  const int ybase[4] = {0, 1024, 5120, 14336};
  const int s = sarr[si], ss = ssarr[si];
  const float yc = (float)(h * (s - 1)) / 63.0f;
  int y0 = (int)yc;
  int y1 = (y0 + 1 < s - 1) ? y0 + 1 : s - 1;
  const float wy = yc - (float)y0;
  const float* base = ys + ybase[si] + (size_t)n * 512 * ss;
  for (int idx = t; idx < 512 * s; idx += 256) {
    int o = idx / s, j = idx - o * s;
    s0[idx] = base[(size_t)o * ss + y0 * s + j];
    s1[idx] = base[(size_t)o * ss + y1 * s + j];
  }
  __syncthreads();
  unsigned short* dstbase = cat + (size_t)(n * 64 + si * 8) * PLANE_ELEMS;
  for (int k = 0; k < 32; ++k) {
    const int g = t + k * 256;             // 0..8191
    const int cbp = g >> 10, rem = g & 1023;
    const int w = rem >> 4, c4 = rem & 15;
    const float xc = (float)(w * (s - 1)) / 63.0f;
    int x0 = (int)xc;
    int x1 = (x0 + 1 < s - 1) ? x0 + 1 : s - 1;
    const float wx = xc - (float)x0;
    unsigned short vv[4];
#pragma unroll
    for (int j = 0; j < 4; ++j) {
      const int o = cbp * 64 + c4 * 4 + j;
      const float a = s0[o * s + x0], b2 = s0[o * s + x1];
      const float c = s1[o * s + x0], d = s1[o * s + x1];
      const float top = a + (b2 - a) * wx;
      const float bot = c + (d - c) * wx;
      vv[j] = f2bf(top + (bot - top) * wy);
    }
    us4 ov; ov.x = vv[0]; ov.y = vv[1]; ov.z = vv[2]; ov.w = vv[3];
    const int q = (h + 1) * PADW + (w + 1);
    const int phys = (((c4 >> 1) ^ (q & 7)) << 3) + ((c4 & 1) << 2);
    *(us4*)(dstbase + (size_t)cbp * PLANE_ELEMS + (size_t)q * 64 + phys) = ov;
  }
}

// ---------------------------------------------------------------------------
// 5) feats -> swizzled bf16 cat (NCHW -> blocked, LDS transpose)
// ---------------------------------------------------------------------------
__global__ __launch_bounds__(256) void fill_feats(const float* __restrict__ feats,
                                                  unsigned short* __restrict__ cat) {
  __shared__ float lds[64][65];
  const int t = threadIdx.x;
  const int b = blockIdx.x;                // n*32 + fb
  const int n = b >> 5, fb = b & 31;
  const int h0 = blockIdx.y * 16;
  const float* src = feats + (size_t)(n * 2048 + fb * 64) * 4096;
  unsigned short* dst = cat + (size_t)(n * 64 + 32 + fb) * PLANE_ELEMS;
  for (int h = h0; h < h0 + 16; ++h) {
#pragma unroll
    for (int k = 0; k < 4; ++k) {
      const int idx4 = t + k * 256;        // 0..1023
      const int c = idx4 >> 4, w4 = idx4 & 15;
      float4 v = ((const float4*)(src + (size_t)c * 4096 + h * 64))[w4];
      lds[c][w4 * 4 + 0] = v.x; lds[c][w4 * 4 + 1] = v.y;
      lds[c][w4 * 4 + 2] = v.z; lds[c][w4 * 4 + 3] = v.w;
    }
    __syncthreads();
#pragma unroll
    for (int k = 0; k < 4; ++k) {
      const int idx4 = t + k * 256;
      const int w = idx4 >> 4, c4 = idx4 & 15;
      unsigned short vv[4];
#pragma unroll
      for (int j = 0; j < 4; ++j) vv[j] = f2bf(lds[c4 * 4 + j][w]);
      us4 ov; ov.x = vv[0]; ov.y = vv[1]; ov.z = vv[2]; ov.w = vv[3];
      const int q = (h + 1) * PADW + (w + 1);
      const int phys = (((c4 >> 1) ^ (q & 7)) << 3) + ((c4 & 1) << 2);
      *(us4*)(dst + (size_t)q * 64 + phys) = ov;
    }
    __syncthreads();
  }
}

// ---------------------------------------------------------------------------
// 6) pack wb fp32 [o][c][3][3] -> bf16 fragment-ordered pk (16x16 layout):
//    pk[((cb*9+tap)*4+ot)*8192 + f*512 + lane*8 + e]
//    f = (local o-pair)*2 + ks; o = wn*64+j*16+lr, k = ks*32+quad*8+e
// ---------------------------------------------------------------------------
__global__ __launch_bounds__(256) void pack_w(const float* __restrict__ wb,
                                              unsigned short* __restrict__ pk) {
  __shared__ float lds[16][577];
  const int t = threadIdx.x;
  const int cb = blockIdx.x;               // 0..63
  const int ot = blockIdx.y;               // 0..3
  for (int ch8 = 0; ch8 < 8; ++ch8) {
    const int o0 = ot * 128 + ch8 * 16;
    __syncthreads();
#pragma unroll
    for (int k = 0; k < 9; ++k) {
      const int idx4 = t + k * 256;        // 0..2303
      const int os = idx4 / 144, c4 = idx4 - os * 144;
      float4 v = ((const float4*)(wb + (size_t)(o0 + os) * 36864 + cb * 576))[c4];
      lds[os][c4 * 4 + 0] = v.x; lds[os][c4 * 4 + 1] = v.y;
      lds[os][c4 * 4 + 2] = v.z; lds[os][c4 * 4 + 3] = v.w;
    }
    __syncthreads();
#pragma unroll
    for (int k = 0; k < 9; ++k) {
      const int g = t + k * 256;           // 0..2303 = tap(9) x os(16) x c4(16)
      const int c4 = g & 15;               // k-chunk: k = c4*4 + j
      const int os = (g >> 4) & 15;        // lr; o = ch8*16 + os
      const int tap = g >> 8;
      unsigned short vv[4];
#pragma unroll
      for (int j = 0; j < 4; ++j) vv[j] = f2bf(lds[os][(c4 * 4 + j) * 9 + tap]);
      us4 ov; ov.x = vv[0]; ov.y = vv[1]; ov.z = vv[2]; ov.w = vv[3];
      // fragment address: f = ch8*2 + (c4>>3); lane = ((c4>>1)&3)*16 + os; e0 = (c4&1)*4
      const size_t dst = ((size_t)(cb * 9 + tap) * 4 + ot) * 8192 +
                         (size_t)(ch8 * 2 + (c4 >> 3)) * 512 +
                         (size_t)(((c4 >> 1) & 3) * 16 + os) * 8 + (c4 & 1) * 4;
      *(us4*)(pk + dst) = ov;
    }
  }
}

// ---------------------------------------------------------------------------
// 7) conv3x3 implicit GEMM: A staged once per cb (4 padded rows, all 9 taps),
//    B register-direct from fragment-ordered pk with EXPLICIT double-buffer
//    (prefetch tap+1 while computing tap). 16x16x32 MFMA, 128x128 tile,
//    split-K=4, atomicAdd epilogue.
// ---------------------------------------------------------------------------
__global__ __launch_bounds__(256, 2) void conv3_kernel(
    const unsigned short* __restrict__ cat, const unsigned short* __restrict__ pk,
    float* __restrict__ C) {
  __shared__ unsigned short As[264 * 64];  // 4 rows x 66 slots x 64ch = 33792 B
  const int t = threadIdx.x;
  const int lane = t & 63;
  const int wave = t >> 6;
  const int lr = lane & 15;
  const int quad = lane >> 4;
  const int bx = blockIdx.x;               // 0..63  M tile (128 pixels = 2 rows)
  const int by = blockIdx.y;               // 0..3   N tile (128 out ch)
  const int bz = blockIdx.z;               // 0..3   split-K (16 cblk each)
  const int n = bx >> 5;
  const int h0 = (bx & 31) << 1;
  const int wm = wave >> 1, wn = wave & 1;

  f32x4 acc[4][4];
#pragma unroll
  for (int i = 0; i < 4; ++i)
#pragma unroll
    for (int j = 0; j < 4; ++j) acc[i][j] = (f32x4)0.0f;

  const uint32_t as_base = (uint32_t)(uintptr_t)(&As[0]);
  const uint8_t* catb = (const uint8_t*)cat;
  const unsigned short* pkw = pk + (size_t)by * 8192 + (size_t)(wn * 8) * 512 +
                              (size_t)lane * 8;

  int tcb = bz * 144;                      // flat cb*9+tap cursor
  const int tcb_last = bz * 144 + 143;
  short8 bfc[8], bfn[8];
  {
    const unsigned short* p0 = pkw + (size_t)tcb * 32768;
#pragma unroll
    for (int f = 0; f < 8; ++f) bfc[f] = *(const short8*)(p0 + f * 512);
  }

  for (int cb2 = 0; cb2 < 16; ++cb2) {
    const int cb = bz * 16 + cb2;
    const uint8_t* srcA = catb +
        ((size_t)(n * 64 + cb) * PLANE_ELEMS + (size_t)(h0 * PADW) * 64) * 2;
    __syncthreads();                       // protect As reuse
    for (int idx = wave; idx < 33; idx += 4)
      load_lds16(srcA + (size_t)idx * 1024 + lane * 16,
                 as_base + (uint32_t)idx * 1024 + lane * 16);
    __syncthreads();
#pragma unroll
    for (int tap = 0; tap < 9; ++tap) {
      // prefetch next tap's B fragments (wraps into next cb; clamped at end)
      const int tnext = (tcb < tcb_last) ? tcb + 1 : tcb_last;
      const unsigned short* pn = pkw + (size_t)tnext * 32768;
#pragma unroll
      for (int f = 0; f < 8; ++f) bfn[f] = *(const short8*)(pn + f * 512);

      const int dh = tap / 3 - 1, dw = tap % 3 - 1;
      const int r = wm + 1 + dh;           // As row 0..3
#pragma unroll
      for (int ks = 0; ks < 2; ++ks) {
        short8 af[4];
#pragma unroll
        for (int i = 0; i < 4; ++i) {
          const int s = i * 16 + lr + 1 + dw;
          const int q = (h0 + r) * PADW + s;   // slot idx -> swizzle key
          const unsigned short* rowp = As + ((r * 66 + s) << 6);
          af[i] = *(const short8*)(rowp + (((ks * 4 + quad) ^ (q & 7)) << 3));
        }
#pragma unroll
        for (int i = 0; i < 4; ++i)
#pragma unroll
          for (int j = 0; j < 4; ++j)
            acc[i][j] = __builtin_amdgcn_mfma_f32_16x16x32_bf16(
                af[i], bfc[j * 2 + ks], acc[i][j], 0, 0, 0);
      }
#pragma unroll
      for (int f = 0; f < 8; ++f) bfc[f] = bfn[f];
      ++tcb;
    }
  }
  // epilogue: C/D layout col = lane&15, row = (lane>>4)*4 + r
  const int row4 = quad * 4;
  const int col = lr;
#pragma unroll
  for (int i = 0; i < 4; ++i) {
    const int m0 = wm * 64 + i * 16 + row4;
#pragma unroll
    for (int j = 0; j < 4; ++j) {
      const int o = by * 128 + wn * 64 + j * 16 + col;
#pragma unroll
      for (int r = 0; r < 4; ++r) {
        const size_t p = (size_t)bx * 128 + m0 + r;
        atomicAdd(&C[p * 512 + o], acc[i][j][r]);
      }
    }
  }
}

// ---------------------------------------------------------------------------
// 8) batch-norm stats over pixels for each of 512 channels
// ---------------------------------------------------------------------------
__global__ __launch_bounds__(256) void bn_stats_kernel(const float* __restrict__ C,
                                                       float* __restrict__ stats) {
  const int t = threadIdx.x;
  const int p0 = blockIdx.x * 32;
  float s0 = 0.f, q0 = 0.f, s1 = 0.f, q1 = 0.f;
  for (int p = p0; p < p0 + 32; ++p) {
    const float a = C[(size_t)p * 512 + t];
    const float b = C[(size_t)p * 512 + t + 256];
    s0 += a; q0 += a * a; s1 += b; q1 += b * b;
  }
  atomicAdd(&stats[t], s0);
  atomicAdd(&stats[t + 256], s1);
  atomicAdd(&stats[512 + t], q0);
  atomicAdd(&stats[512 + t + 256], q1);
}

// ---------------------------------------------------------------------------
// 9) BN apply + leaky_relu + NHWC -> NCHW transpose into d_out
// ---------------------------------------------------------------------------
__global__ __launch_bounds__(256) void bn_apply_kernel(
    const float* __restrict__ C, const float* __restrict__ stats,
    const float* __restrict__ gb, const float* __restrict__ bb,
    float* __restrict__ out) {
  __shared__ float lds[64][65];
  __shared__ float sc_s[64], sh_s[64];
  const int t = threadIdx.x;
  const int p0 = blockIdx.x * 64;          // 64 pixels = one (n,h) row
  const int o0 = blockIdx.y * 64;
  if (t < 64) {
    const int o = o0 + t;
    const float mean = stats[o] * (1.0f / 8192.0f);
    float var = stats[512 + o] * (1.0f / 8192.0f) - mean * mean;
    var = fmaxf(var, 0.0f);
    const float rstd = rsqrtf(var + 1e-5f);
    const float sc = rstd * gb[o];
    sc_s[t] = sc;
    sh_s[t] = bb[o] - mean * sc;
  }
#pragma unroll
  for (int k = 0; k < 4; ++k) {
    const int idx4 = t + k * 256;
    const int ps = idx4 >> 4, o4 = idx4 & 15;
    float4 v = ((const float4*)(C + (size_t)(p0 + ps) * 512 + o0))[o4];
    lds[ps][o4 * 4 + 0] = v.x; lds[ps][o4 * 4 + 1] = v.y;
    lds[ps][o4 * 4 + 2] = v.z; lds[ps][o4 * 4 + 3] = v.w;
  }
  __syncthreads();
  const int n = p0 >> 12, h = (p0 >> 6) & 63;
#pragma unroll
  for (int k = 0; k < 4; ++k) {
    const int idx4 = t + k * 256;
    const int os = idx4 >> 4, w4 = idx4 & 15;
    const float sc = sc_s[os], sh = sh_s[os];
    float vv[4];
#pragma unroll
    for (int j = 0; j < 4; ++j) {
      float v = lds[w4 * 4 + j][os] * sc + sh;
      vv[j] = (v >= 0.f) ? v : 0.01f * v;
    }
    float4 r; r.x = vv[0]; r.y = vv[1]; r.z = vv[2]; r.w = vv[3];
    *(float4*)(out + ((size_t)(n * 512 + o0 + os)) * 4096 + h * 64 + w4 * 4) = r;
  }
}

// ---------------------------------------------------------------------------
extern "C" void kernel_launch(void* const* d_in, const int* in_sizes, int n_in,
                              void* d_out, int out_size, void* d_ws, size_t ws_size,
                              hipStream_t stream) {
  (void)in_sizes; (void)n_in; (void)out_size; (void)ws_size;
  const float* feats = (const float*)d_in[0];
  const float* w0 = (const float*)d_in[1];
  const float* g0 = (const float*)d_in[2];
  const float* b0 = (const float*)d_in[3];
  const float* w1 = (const float*)d_in[4];
  const float* g1 = (const float*)d_in[5];
  const float* b1 = (const float*)d_in[6];
  const float* w2 = (const float*)d_in[7];
  const float* g2 = (const float*)d_in[8];
  const float* b2 = (const float*)d_in[9];
  const float* w3 = (const float*)d_in[10];
  const float* g3 = (const float*)d_in[11];
  const float* b3 = (const float*)d_in[12];
  const float* wb = (const float*)d_in[13];
  const float* gb = (const float*)d_in[14];
  const float* bb = (const float*)d_in[15];

  uint8_t* ws = (uint8_t*)d_ws;
  float* pooled = (float*)(ws + POOLED_OFF);
  float* ys = (float*)(ws + YS_OFF);
  float* stats = (float*)(ws + STATS_OFF);
  unsigned short* cat = (unsigned short*)(ws + CAT_OFF);
  unsigned short* pk = (unsigned short*)(ws + PACKED_OFF);
  float* C = (float*)(ws + CBUF_OFF);
  float* outp = (float*)d_out;

  hipMemsetAsync(stats, 0, 4096, stream);
  hipMemsetAsync(C, 0, CBUF_BYTES, stream);

  pool_kernel<<<4096, 256, 0, stream>>>(feats, pooled);
  conv1x1_kernel<<<400, 256, 0, stream>>>(pooled, w0, w1, w2, w3, ys);
  bn_small_kernel<<<4, 512, 0, stream>>>(ys, g0, b0, g1, b1, g2, b2, g3, b3);
  zero_borders<<<128, 256, 0, stream>>>(cat);
  fill_priors<<<dim3(128, 4), 256, 0, stream>>>(ys, cat);
  fill_feats<<<dim3(64, 4), 256, 0, stream>>>(feats, cat);
  pack_w<<<dim3(64, 4), 256, 0, stream>>>(wb, pk);
  conv3_kernel<<<dim3(64, 4, 4), 256, 0, stream>>>(cat, pk, C);
  bn_stats_kernel<<<256, 256, 0, stream>>>(C, stats);
  bn_apply_kernel<<<dim3(128, 8), 256, 0, stream>>>(C, stats, gb, bb, outp);
}

// Round 8
// 600.003 us; speedup vs baseline: 1.2250x; 1.1098x over previous
//
#include <hip/hip_runtime.h>
#include <stdint.h>

// ---------------------------------------------------------------------------
// PSPModule: pool(1,2,3,6) -> conv1x1+BN+lrelu -> bilinear upsample -> concat
//            -> conv3x3 (bf16 MFMA implicit GEMM) -> BN+lrelu
// Round 8: conv3+pack_w reverted to r3 (best: 282us, MfmaUtil 51). Tail attack:
// conv1x1 rewritten as bf16 MFMA GEMM (pool emits padded bf16 A rows; wpack1
// emits W in B-fragment order) -> W traffic 420 MB -> ~25 MB.
// ---------------------------------------------------------------------------

typedef short short8 __attribute__((ext_vector_type(8)));
typedef float f32x4 __attribute__((ext_vector_type(4)));
typedef unsigned short us4 __attribute__((ext_vector_type(4)));

#define PADW   66
#define PLANE  (PADW*PADW)        // 4356 slots of 64ch
#define PLANE_ELEMS ((size_t)PLANE*64)

// workspace layout (bytes)
#define APOOL_OFF   0u                       // bf16[144*2048]          589824
#define YS_OFF      819200u                  // float[51200]            204800
#define STATS_OFF   1024000u                 // float[1024]             4096
#define CAT_OFF     1048576u                 // bf16[128*4356*64]       71368704
#define CAT_BYTES   71368704u
#define PACKED_OFF  (CAT_OFF + CAT_BYTES)    // bf16[576*4*128*64]      37748736
#define PACKED_BYTES 37748736u
#define CBUF_OFF    (PACKED_OFF + PACKED_BYTES) // float[8192*512]      16777216
#define CBUF_BYTES  16777216u
#define WP_OFF      (CBUF_OFF + CBUF_BYTES)  // bf16[4*32*64*512]       8388608

__device__ __forceinline__ unsigned short f2bf(float x) {
  unsigned int u = __float_as_uint(x);
  unsigned int r = (u + 0x7fffu + ((u >> 16) & 1u)) >> 16;
  return (unsigned short)r;
}

__device__ __forceinline__ void load_lds16(const void* g, uint32_t lds_off) {
  __builtin_amdgcn_global_load_lds(
      (__attribute__((address_space(1))) void*)(uintptr_t)g,
      (__attribute__((address_space(3))) void*)(uintptr_t)lds_off,
      16, 0, 0);
}

// ---------------------------------------------------------------------------
// 1) adaptive avg pool -> padded bf16 A rows (row = si-base + n*ss + pos)
// ---------------------------------------------------------------------------
__global__ __launch_bounds__(256) void pool_kernel(const float* __restrict__ feats,
                                                   unsigned short* __restrict__ apool) {
  __shared__ float rowtot[64];
  __shared__ float rowseg2[64][2];
  __shared__ float rowseg3[64][3];
  __shared__ float rowseg6[64][6];
  const int t = threadIdx.x;
  const int b = blockIdx.x;                 // n*2048 + c
  const float* plane = feats + (size_t)b * 4096;
  const int h = t >> 2, w0 = (t & 3) << 4;
  const int ws3[3] = {0, 21, 42}, we3[3] = {22, 43, 64};
  const int ws6[6] = {0, 10, 21, 32, 42, 53}, we6[6] = {11, 22, 32, 43, 54, 64};
  float p3[3] = {0.f, 0.f, 0.f};
  float p6[6] = {0.f, 0.f, 0.f, 0.f, 0.f, 0.f};
  float tot = 0.f;
  const float4* row = (const float4*)(plane + h * 64 + w0);
#pragma unroll
  for (int i4 = 0; i4 < 4; ++i4) {
    float4 v = row[i4];
    float vals[4] = {v.x, v.y, v.z, v.w};
#pragma unroll
    for (int j = 0; j < 4; ++j) {
      const int w = w0 + i4 * 4 + j;
      const float x = vals[j];
      tot += x;
#pragma unroll
      for (int q = 0; q < 3; ++q) if (w >= ws3[q] && w < we3[q]) p3[q] += x;
#pragma unroll
      for (int q = 0; q < 6; ++q) if (w >= ws6[q] && w < we6[q]) p6[q] += x;
    }
  }
  float pair = tot + __shfl_down(tot, 1, 4);
  float tot4 = pair + __shfl_down(pair, 2, 4);
#pragma unroll
  for (int q = 0; q < 3; ++q) {
    p3[q] += __shfl_down(p3[q], 1, 4);
    p3[q] += __shfl_down(p3[q], 2, 4);
  }
#pragma unroll
  for (int q = 0; q < 6; ++q) {
    p6[q] += __shfl_down(p6[q], 1, 4);
    p6[q] += __shfl_down(p6[q], 2, 4);
  }
  if ((t & 3) == 0) {
    rowtot[h] = tot4;
    rowseg2[h][0] = pair;
#pragma unroll
    for (int q = 0; q < 3; ++q) rowseg3[h][q] = p3[q];
#pragma unroll
    for (int q = 0; q < 6; ++q) rowseg6[h][q] = p6[q];
  }
  if ((t & 3) == 2) rowseg2[h][1] = pair;
  __syncthreads();
  if (t < 50) {
    float s = 0.f;
    float inv;
    int mrow;
    const int n = b >> 11, c = b & 2047;
    if (t == 0) {
      for (int r = 0; r < 64; ++r) s += rowtot[r];
      inv = 1.0f / 4096.0f;
      mrow = n;                                    // si0 base 0, ss 1
    } else if (t < 5) {
      const int qh = (t - 1) >> 1, qw = (t - 1) & 1;
      for (int r = qh * 32; r < qh * 32 + 32; ++r) s += rowseg2[r][qw];
      inv = 1.0f / 1024.0f;
      mrow = 16 + n * 4 + (t - 1);                 // si1 base 16, ss 4
    } else if (t < 14) {
      const int p = t - 5, qh = p / 3, qw = p % 3;
      for (int r = ws3[qh]; r < we3[qh]; ++r) s += rowseg3[r][qw];
      inv = 1.0f / ((float)(we3[qh] - ws3[qh]) * (float)(we3[qw] - ws3[qw]));
      mrow = 32 + n * 9 + p;                       // si2 base 32, ss 9
    } else {
      const int p = t - 14, qh = p / 6, qw = p % 6;
      for (int r = ws6[qh]; r < we6[qh]; ++r) s += rowseg6[r][qw];
      inv = 1.0f / ((float)(we6[qh] - ws6[qh]) * (float)(we6[qw] - ws6[qw]));
      mrow = 64 + n * 36 + p;                      // si3 base 64, ss 36
    }
    apool[(size_t)mrow * 2048 + c] = f2bf(s * inv);
  }
}

// ---------------------------------------------------------------------------
// 1.5) wpack1: W fp32 [512][2048] x4 -> bf16 16x16x32 B-fragment order
//      wp[((si*32+ot)*64 + kstep)*512 + (quad*16 + o16)*8 + e]
// ---------------------------------------------------------------------------
__global__ __launch_bounds__(256) void wpack1(
    const float* __restrict__ w0, const float* __restrict__ w1,
    const float* __restrict__ w2, const float* __restrict__ w3,
    unsigned short* __restrict__ wp) {
  const int t = threadIdx.x;
  const int si = blockIdx.x >> 5;
  const int ot = blockIdx.x & 31;          // 16-o tile
  const float* Wt = (si == 0) ? w0 : (si == 1) ? w1 : (si == 2) ? w2 : w3;
  const float* base = Wt + (size_t)(ot * 16) * 2048;
  unsigned short* dst0 = wp + (size_t)(si * 32 + ot) * 64 * 512;
#pragma unroll
  for (int i = 0; i < 32; ++i) {
    const int flat = t + i * 256;          // 0..8191 = o(16) x k4(512)
    const int o = flat >> 9, k4 = flat & 511;
    float4 v = ((const float4*)(base + (size_t)o * 2048))[k4];
    unsigned short vv[4] = {f2bf(v.x), f2bf(v.y), f2bf(v.z), f2bf(v.w)};
    us4 ov; ov.x = vv[0]; ov.y = vv[1]; ov.z = vv[2]; ov.w = vv[3];
    const int kstep = k4 >> 3, quad = (k4 >> 1) & 3, e0 = (k4 & 1) * 4;
    *(us4*)(dst0 + (size_t)kstep * 512 + (quad * 16 + o) * 8 + e0) = ov;
  }
}

// ---------------------------------------------------------------------------
// 2) conv1x1 as bf16 MFMA GEMM: 9 M-tiles(16) x 8 N-tiles(64), wave = 16 o's
// ---------------------------------------------------------------------------
__global__ __launch_bounds__(256) void conv1x1_mfma(
    const unsigned short* __restrict__ apool, const unsigned short* __restrict__ wp,
    float* __restrict__ ys) {
  const int t = threadIdx.x;
  const int lane = t & 63;
  const int wv = t >> 6;
  const int lr = lane & 15;
  const int quad = lane >> 4;
  const int mt = blockIdx.x;               // 0..8
  const int nt = blockIdx.y;               // 0..7
  const int sitab[9] = {0, 1, 2, 2, 3, 3, 3, 3, 3};
  const int mbtab[9] = {0, 16, 32, 48, 64, 80, 96, 112, 128};
  const int si = sitab[mt], mbase = mbtab[mt];
  const int otile = nt * 4 + wv;           // 0..31
  const unsigned short* wrec = wp + (size_t)(si * 32 + otile) * 64 * 512 +
                               (size_t)lane * 8;
  const unsigned short* arow = apool + (size_t)(mbase + lr) * 2048 + quad * 8;
  f32x4 acc = (f32x4)0.0f;
#pragma unroll 4
  for (int k = 0; k < 64; ++k) {
    short8 a = *(const short8*)(arow + k * 32);
    short8 b = *(const short8*)(wrec + (size_t)k * 512);
    acc = __builtin_amdgcn_mfma_f32_16x16x32_bf16(a, b, acc, 0, 0, 0);
  }
  const int ssarr[4] = {1, 4, 9, 36};
  const int mstart[4] = {0, 16, 32, 64};
  const int ybase[4] = {0, 1024, 5120, 14336};
  const int ss = ssarr[si];
  const int o = otile * 16 + lr;
#pragma unroll
  for (int r = 0; r < 4; ++r) {
    const int mr = (mbase - mstart[si]) + quad * 4 + r;
    if (mr < 2 * ss) {
      const int n = mr / ss, pos = mr - n * ss;
      ys[ybase[si] + (size_t)(n * 512 + o) * ss + pos] = acc[r];
    }
  }
}

// ---------------------------------------------------------------------------
// 3) BN (batch stats) + leaky_relu on tiny pooled maps, in place
// ---------------------------------------------------------------------------
__global__ __launch_bounds__(512) void bn_small_kernel(
    float* __restrict__ ys, const float* __restrict__ g0, const float* __restrict__ b0,
    const float* __restrict__ g1, const float* __restrict__ b1,
    const float* __restrict__ g2, const float* __restrict__ b2,
    const float* __restrict__ g3, const float* __restrict__ b3) {
  const int si = blockIdx.x;
  const int o = threadIdx.x;               // 0..511
  const int ssarr[4] = {1, 4, 9, 36};
  const int ybase[4] = {0, 1024, 5120, 14336};
  const int ss = ssarr[si];
  const int M = 2 * ss;
  float* base0 = ys + ybase[si] + (size_t)o * ss;
  float* base1 = ys + ybase[si] + (size_t)(512 + o) * ss;
  float sum = 0.f, sq = 0.f;
  for (int p = 0; p < ss; ++p) { float v = base0[p]; sum += v; sq += v * v; }
  for (int p = 0; p < ss; ++p) { float v = base1[p]; sum += v; sq += v * v; }
  const float mean = sum / (float)M;
  float var = sq / (float)M - mean * mean;
  var = fmaxf(var, 0.0f);
  const float rstd = rsqrtf(var + 1e-5f);
  const float* gp = (si == 0) ? g0 : (si == 1) ? g1 : (si == 2) ? g2 : g3;
  const float* bp = (si == 0) ? b0 : (si == 1) ? b1 : (si == 2) ? b2 : b3;
  const float sc = rstd * gp[o];
  const float sh = bp[o] - mean * sc;
  for (int p = 0; p < ss; ++p) {
    float y = base0[p] * sc + sh; base0[p] = (y >= 0.f) ? y : 0.01f * y;
  }
  for (int p = 0; p < ss; ++p) {
    float y = base1[p] * sc + sh; base1[p] = (y >= 0.f) ? y : 0.01f * y;
  }
}

// ---------------------------------------------------------------------------
// 3.5) zero the 1-pixel borders of all 128 cat planes (swizzle-invariant)
// ---------------------------------------------------------------------------
__global__ __launch_bounds__(256) void zero_borders(unsigned short* __restrict__ cat) {
  const int t = threadIdx.x;
  unsigned short* base = cat + (size_t)blockIdx.x * PLANE_ELEMS;
  for (int idx = t; idx < 4160; idx += 256) {   // 260 border slots x 16 us4
    const int slot = idx >> 4, c4 = idx & 15;
    int q;
    if (slot < 66) q = slot;
    else if (slot < 132) q = 65 * 66 + (slot - 66);
    else { const int k = slot - 132; q = (1 + (k >> 1)) * 66 + (k & 1) * 65; }
    us4 z = {0, 0, 0, 0};
    *(us4*)(base + (size_t)q * 64 + c4 * 4) = z;
  }
}

// ---------------------------------------------------------------------------
// 4) bilinear (align_corners) upsample of priors into swizzled bf16 cat
// ---------------------------------------------------------------------------
__global__ __launch_bounds__(256) void fill_priors(const float* __restrict__ ys,
                                                   unsigned short* __restrict__ cat) {
  __shared__ float s0[3072], s1[3072];
  const int t = threadIdx.x;
  const int bx = blockIdx.x;               // n*64 + h
  const int si = blockIdx.y;               // 0..3
  const int n = bx >> 6, h = bx & 63;
  const int sarr[4] = {1, 2, 3, 6};
  const int ssarr[4] = {1, 4, 9, 36};
  const int ybase[4] = {0, 1024, 5120, 14336};
  const int s = sarr[si], ss = ssarr[si];
  const float yc = (float)(h * (s - 1)) / 63.0f;
  int y0 = (int)yc;
  int y1 = (y0 + 1 < s - 1) ? y0 + 1 : s - 1;
  const float wy = yc - (float)y0;
  const float* base = ys + ybase[si] + (size_t)n * 512 * ss;
  for (int idx = t; idx < 512 * s; idx += 256) {
    int o = idx / s, j = idx - o * s;
    s0[idx] = base[(size_t)o * ss + y0 * s + j];
    s1[idx] = base[(size_t)o * ss + y1 * s + j];
  }
  __syncthreads();
  unsigned short* dstbase = cat + (size_t)(n * 64 + si * 8) * PLANE_ELEMS;
  for (int k = 0; k < 32; ++k) {
    const int g = t + k * 256;             // 0..8191
    const int cbp = g >> 10, rem = g & 1023;
    const int w = rem >> 4, c4 = rem & 15;
    const float xc = (float)(w * (s - 1)) / 63.0f;
    int x0 = (int)xc;
    int x1 = (x0 + 1 < s - 1) ? x0 + 1 : s - 1;
    const float wx = xc - (float)x0;
    unsigned short vv[4];
#pragma unroll
    for (int j = 0; j < 4; ++j) {
      const int o = cbp * 64 + c4 * 4 + j;
      const float a = s0[o * s + x0], b2 = s0[o * s + x1];
      const float c = s1[o * s + x0], d = s1[o * s + x1];
      const float top = a + (b2 - a) * wx;
      const float bot = c + (d - c) * wx;
      vv[j] = f2bf(top + (bot - top) * wy);
    }
    us4 ov; ov.x = vv[0]; ov.y = vv[1]; ov.z = vv[2]; ov.w = vv[3];
    const int q = (h + 1) * PADW + (w + 1);
    const int phys = (((c4 >> 1) ^ (q & 7)) << 3) + ((c4 & 1) << 2);
    *(us4*)(dstbase + (size_t)cbp * PLANE_ELEMS + (size_t)q * 64 + phys) = ov;
  }
}

// ---------------------------------------------------------------------------
// 5) feats -> swizzled bf16 cat (NCHW -> blocked, LDS transpose)
// ---------------------------------------------------------------------------
__global__ __launch_bounds__(256) void fill_feats(const float* __restrict__ feats,
                                                  unsigned short* __restrict__ cat) {
  __shared__ float lds[64][65];
  const int t = threadIdx.x;
  const int b = blockIdx.x;                // n*32 + fb
  const int n = b >> 5, fb = b & 31;
  const int h0 = blockIdx.y * 16;
  const float* src = feats + (size_t)(n * 2048 + fb * 64) * 4096;
  unsigned short* dst = cat + (size_t)(n * 64 + 32 + fb) * PLANE_ELEMS;
  for (int h = h0; h < h0 + 16; ++h) {
#pragma unroll
    for (int k = 0; k < 4; ++k) {
      const int idx4 = t + k * 256;        // 0..1023
      const int c = idx4 >> 4, w4 = idx4 & 15;
      float4 v = ((const float4*)(src + (size_t)c * 4096 + h * 64))[w4];
      lds[c][w4 * 4 + 0] = v.x; lds[c][w4 * 4 + 1] = v.y;
      lds[c][w4 * 4 + 2] = v.z; lds[c][w4 * 4 + 3] = v.w;
    }
    __syncthreads();
#pragma unroll
    for (int k = 0; k < 4; ++k) {
      const int idx4 = t + k * 256;
      const int w = idx4 >> 4, c4 = idx4 & 15;
      unsigned short vv[4];
#pragma unroll
      for (int j = 0; j < 4; ++j) vv[j] = f2bf(lds[c4 * 4 + j][w]);
      us4 ov; ov.x = vv[0]; ov.y = vv[1]; ov.z = vv[2]; ov.w = vv[3];
      const int q = (h + 1) * PADW + (w + 1);
      const int phys = (((c4 >> 1) ^ (q & 7)) << 3) + ((c4 & 1) << 2);
      *(us4*)(dst + (size_t)q * 64 + phys) = ov;
    }
    __syncthreads();
  }
}

// ---------------------------------------------------------------------------
// 6) pack wb fp32 [o][c][3][3] -> swizzled bf16 [cb*9+tap][ot][o128][k64]
// ---------------------------------------------------------------------------
__global__ __launch_bounds__(256) void pack_w(const float* __restrict__ wb,
                                              unsigned short* __restrict__ pk) {
  __shared__ float lds[16][577];
  const int t = threadIdx.x;
  const int cb = blockIdx.x;               // 0..63
  const int ot = blockIdx.y;               // 0..3
  for (int ch8 = 0; ch8 < 8; ++ch8) {
    const int o0 = ot * 128 + ch8 * 16;
    __syncthreads();
#pragma unroll
    for (int k = 0; k < 9; ++k) {
      const int idx4 = t + k * 256;        // 0..2303
      const int os = idx4 / 144, c4 = idx4 - os * 144;
      float4 v = ((const float4*)(wb + (size_t)(o0 + os) * 36864 + cb * 576))[c4];
      lds[os][c4 * 4 + 0] = v.x; lds[os][c4 * 4 + 1] = v.y;
      lds[os][c4 * 4 + 2] = v.z; lds[os][c4 * 4 + 3] = v.w;
    }
    __syncthreads();
#pragma unroll
    for (int k = 0; k < 9; ++k) {
      const int g = t + k * 256;           // 0..2303 = tap(9) x os(16) x c4(16)
      const int c4 = g & 15;
      const int os = (g >> 4) & 15;
      const int tap = g >> 8;
      unsigned short vv[4];
#pragma unroll
      for (int j = 0; j < 4; ++j) vv[j] = f2bf(lds[os][(c4 * 4 + j) * 9 + tap]);
      us4 ov; ov.x = vv[0]; ov.y = vv[1]; ov.z = vv[2]; ov.w = vv[3];
      const int phys = (((c4 >> 1) ^ (os & 7)) << 3) + ((c4 & 1) << 2);
      const size_t dst = ((size_t)(cb * 9 + tap) * 4 + ot) * 8192 +
                         (size_t)(ch8 * 16 + os) * 64 + phys;
      *(us4*)(pk + dst) = ov;
    }
  }
}

// ---------------------------------------------------------------------------
// 7) conv3x3 implicit GEMM (r3): 16x16x32 MFMA, 128x128 tile, split-K=4,
//    swizzled LDS (conflict-free b128), fp32 atomicAdd epilogue into C[p][o]
// ---------------------------------------------------------------------------
__global__ __launch_bounds__(256, 2) void conv3_kernel(
    const unsigned short* __restrict__ cat, const unsigned short* __restrict__ pk,
    float* __restrict__ C) {
  __shared__ unsigned short As[128 * 64];  // [pixel][k]  (16B chunks swizzled)
  __shared__ unsigned short Bs[128 * 64];  // [o][k]      (16B chunks swizzled)
  const int t = threadIdx.x;
  const int lane = t & 63;
  const int wave = t >> 6;
  const int lr = lane & 15;
  const int quad = lane >> 4;
  const int sB = lane & 7;
  const int bx = blockIdx.x;               // 0..63  M tile (128 pixels = 2 rows)
  const int by = blockIdx.y;               // 0..3   N tile (128 out ch)
  const int bz = blockIdx.z;               // 0..3   split-K (16 cblk each)
  const int n = bx >> 5;
  const int h0 = (bx & 31) << 1;
  const int wm = wave >> 1, wn = wave & 1;

  f32x4 acc[4][4];
#pragma unroll
  for (int i = 0; i < 4; ++i)
#pragma unroll
    for (int j = 0; j < 4; ++j) acc[i][j] = (f32x4)0.0f;

  const uint32_t as_lds = (uint32_t)(uintptr_t)(&As[0]) + wave * 4096;
  const uint32_t bs_lds = (uint32_t)(uintptr_t)(&Bs[0]) + wave * 4096;
  const uint8_t* catb = (const uint8_t*)cat;
  const uint8_t* pkb = (const uint8_t*)pk;
  const size_t aq_off = ((size_t)(wave >> 1) * PADW * 64 + (size_t)(wave & 1) * 32 * 64) * 2 +
                        (size_t)lane * 16;
  const size_t bq_off = (size_t)wave * 4096 + (size_t)lane * 16;

  for (int cb2 = 0; cb2 < 16; ++cb2) {
    const int cb = bz * 16 + cb2;
    const uint8_t* planeb = catb + (size_t)(n * 64 + cb) * (PLANE_ELEMS * 2);
    for (int tap = 0; tap < 9; ++tap) {
      const int dh = tap / 3 - 1, dw = tap % 3 - 1;
      const int q0 = (h0 + 1 + dh) * PADW + (1 + dw);
      // swizzle key for the M-row this wave reads: q(m) = q0 + wm*PADW + (i*16+lr)
      const int sA = (q0 + wm * PADW + lr) & 7;
      __syncthreads();
      const uint8_t* ga = planeb + ((size_t)q0 * 64) * 2 + aq_off;
      const uint8_t* gb = pkb +
          (((size_t)(cb * 9 + tap) * 4 + by) * 8192) * 2 + bq_off;
#pragma unroll
      for (int i = 0; i < 4; ++i) load_lds16(ga + i * 1024, as_lds + i * 1024);
#pragma unroll
      for (int i = 0; i < 4; ++i) load_lds16(gb + i * 1024, bs_lds + i * 1024);
      __syncthreads();
#pragma unroll
      for (int ks = 0; ks < 2; ++ks) {
        const int cA = ((ks * 4 + quad) ^ sA) << 3;
        const int cB = ((ks * 4 + quad) ^ sB) << 3;
        short8 af[4], bf[4];
#pragma unroll
        for (int i = 0; i < 4; ++i)
          af[i] = *(const short8*)(As + (size_t)(wm * 64 + i * 16 + lr) * 64 + cA);
#pragma unroll
        for (int j = 0; j < 4; ++j)
          bf[j] = *(const short8*)(Bs + (size_t)(wn * 64 + j * 16 + lr) * 64 + cB);
#pragma unroll
        for (int i = 0; i < 4; ++i)
#pragma unroll
          for (int j = 0; j < 4; ++j)
            acc[i][j] = __builtin_amdgcn_mfma_f32_16x16x32_bf16(af[i], bf[j],
                                                                acc[i][j], 0, 0, 0);
      }
    }
  }
  // epilogue: C/D layout col = lane&15, row = (lane>>4)*4 + r
  const int row4 = quad * 4;
  const int col = lr;
#pragma unroll
  for (int i = 0; i < 4; ++i) {
    const int m0 = wm * 64 + i * 16 + row4;
#pragma unroll
    for (int j = 0; j < 4; ++j) {
      const int o = by * 128 + wn * 64 + j * 16 + col;
#pragma unroll
      for (int r = 0; r < 4; ++r) {
        const size_t p = (size_t)bx * 128 + m0 + r;
        atomicAdd(&C[p * 512 + o], acc[i][j][r]);
      }
    }
  }
}

// ---------------------------------------------------------------------------
// 8) batch-norm stats over pixels for each of 512 channels
// ---------------------------------------------------------------------------
__global__ __launch_bounds__(256) void bn_stats_kernel(const float* __restrict__ C,
                                                       float* __restrict__ stats) {
  const int t = threadIdx.x;
  const int p0 = blockIdx.x * 32;
  float s0 = 0.f, q0 = 0.f, s1 = 0.f, q1 = 0.f;
  for (int p = p0; p < p0 + 32; ++p) {
    const float a = C[(size_t)p * 512 + t];
    const float b = C[(size_t)p * 512 + t + 256];
    s0 += a; q0 += a * a; s1 += b; q1 += b * b;
  }
  atomicAdd(&stats[t], s0);
  atomicAdd(&stats[t + 256], s1);
  atomicAdd(&stats[512 + t], q0);
  atomicAdd(&stats[512 + t + 256], q1);
}

// ---------------------------------------------------------------------------
// 9) BN apply + leaky_relu + NHWC -> NCHW transpose into d_out
// ---------------------------------------------------------------------------
__global__ __launch_bounds__(256) void bn_apply_kernel(
    const float* __restrict__ C, const float* __restrict__ stats,
    const float* __restrict__ gb, const float* __restrict__ bb,
    float* __restrict__ out) {
  __shared__ float lds[64][65];
  __shared__ float sc_s[64], sh_s[64];
  const int t = threadIdx.x;
  const int p0 = blockIdx.x * 64;          // 64 pixels = one (n,h) row
  const int o0 = blockIdx.y * 64;
  if (t < 64) {
    const int o = o0 + t;
    const float mean = stats[o] * (1.0f / 8192.0f);
    float var = stats[512 + o] * (1.0f / 8192.0f) - mean * mean;
    var = fmaxf(var, 0.0f);
    const float rstd = rsqrtf(var + 1e-5f);
    const float sc = rstd * gb[o];
    sc_s[t] = sc;
    sh_s[t] = bb[o] - mean * sc;
  }
#pragma unroll
  for (int k = 0; k < 4; ++k) {
    const int idx4 = t + k * 256;
    const int ps = idx4 >> 4, o4 = idx4 & 15;
    float4 v = ((const float4*)(C + (size_t)(p0 + ps) * 512 + o0))[o4];
    lds[ps][o4 * 4 + 0] = v.x; lds[ps][o4 * 4 + 1] = v.y;
    lds[ps][o4 * 4 + 2] = v.z; lds[ps][o4 * 4 + 3] = v.w;
  }
  __syncthreads();
  const int n = p0 >> 12, h = (p0 >> 6) & 63;
#pragma unroll
  for (int k = 0; k < 4; ++k) {
    const int idx4 = t + k * 256;
    const int os = idx4 >> 4, w4 = idx4 & 15;
    const float sc = sc_s[os], sh = sh_s[os];
    float vv[4];
#pragma unroll
    for (int j = 0; j < 4; ++j) {
      float v = lds[w4 * 4 + j][os] * sc + sh;
      vv[j] = (v >= 0.f) ? v : 0.01f * v;
    }
    float4 r; r.x = vv[0]; r.y = vv[1]; r.z = vv[2]; r.w = vv[3];
    *(float4*)(out + ((size_t)(n * 512 + o0 + os)) * 4096 + h * 64 + w4 * 4) = r;
  }
}

// ---------------------------------------------------------------------------
extern "C" void kernel_launch(void* const* d_in, const int* in_sizes, int n_in,
                              void* d_out, int out_size, void* d_ws, size_t ws_size,
                              hipStream_t stream) {
  (void)in_sizes; (void)n_in; (void)out_size; (void)ws_size;
  const float* feats = (const float*)d_in[0];
  const float* w0 = (const float*)d_in[1];
  const float* g0 = (const float*)d_in[2];
  const float* b0 = (const float*)d_in[3];
  const float* w1 = (const float*)d_in[4];
  const float* g1 = (const float*)d_in[5];
  const float* b1 = (const float*)d_in[6];
  const float* w2 = (const float*)d_in[7];
  const float* g2 = (const float*)d_in[8];
  const float* b2 = (const float*)d_in[9];
  const float* w3 = (const float*)d_in[10];
  const float* g3 = (const float*)d_in[11];
  const float* b3 = (const float*)d_in[12];
  const float* wb = (const float*)d_in[13];
  const float* gb = (const float*)d_in[14];
  const float* bb = (const float*)d_in[15];

  uint8_t* ws = (uint8_t*)d_ws;
  unsigned short* apool = (unsigned short*)(ws + APOOL_OFF);
  float* ys = (float*)(ws + YS_OFF);
  float* stats = (float*)(ws + STATS_OFF);
  unsigned short* cat = (unsigned short*)(ws + CAT_OFF);
  unsigned short* pk = (unsigned short*)(ws + PACKED_OFF);
  float* C = (float*)(ws + CBUF_OFF);
  unsigned short* wp = (unsigned short*)(ws + WP_OFF);
  float* outp = (float*)d_out;

  hipMemsetAsync(apool, 0, 144 * 2048 * 2, stream);
  hipMemsetAsync(stats, 0, 4096, stream);
  hipMemsetAsync(C, 0, CBUF_BYTES, stream);

  pool_kernel<<<4096, 256, 0, stream>>>(feats, apool);
  wpack1<<<128, 256, 0, stream>>>(w0, w1, w2, w3, wp);
  conv1x1_mfma<<<dim3(9, 8), 256, 0, stream>>>(apool, wp, ys);
  bn_small_kernel<<<4, 512, 0, stream>>>(ys, g0, b0, g1, b1, g2, b2, g3, b3);
  zero_borders<<<128, 256, 0, stream>>>(cat);
  fill_priors<<<dim3(128, 4), 256, 0, stream>>>(ys, cat);
  fill_feats<<<dim3(64, 4), 256, 0, stream>>>(feats, cat);
  pack_w<<<dim3(64, 4), 256, 0, stream>>>(wb, pk);
  conv3_kernel<<<dim3(64, 4, 4), 256, 0, stream>>>(cat, pk, C);
  bn_stats_kernel<<<256, 256, 0, stream>>>(C, stats);
  bn_apply_kernel<<<dim3(128, 8), 256, 0, stream>>>(C, stats, gb, bb, outp);
}